// Round 4
// baseline (69777.606 us; speedup 1.0000x reference)
//
#include <hip/hip_runtime.h>

// LSTM T=4096, IN=32, H=512, OUT=32, 3 layers + projection.
// R4: row-per-wave layout. 96 WGs x 512 thr, layer = blk>>5, g = blk&31.
//   WG owns 16 h-columns; wave wv owns columns {g*16+2wv, g*16+2wv+1} and
//   their 8 gate rows. lane = row_local*8 + j: row_local = gate*2+cl,
//   j = k-chunk (8 lanes x 128 k for layers 1/2; x 64 k + 4 x-k for layer 0).
//   - Full row dot inside one wave -> 3 shfl_xor reduce, NO cross-wave part[],
//     NO second barrier, no wave0-serialized tail (R3's ~500cyc/step).
//   - One __syncthreads per step via double-buffered h_lds.
//   - Cross-WG handoff: packed u64 {seq-tag:32 | value:32} relaxed agent-scope
//     atomics (no cache-wide fences; correct under XCD L2 non-coherence).
//   - Weights register-pinned (asm), staggered LDS reads (bank-conflict-free).

#define T_SEQ 4096
#define HDIM  512
#define NWG_L 32
#define NTH   512

typedef unsigned long long u64;

__device__ __forceinline__ u64 cohLoad(const u64* p) {
    return __hip_atomic_load(p, __ATOMIC_RELAXED, __HIP_MEMORY_SCOPE_AGENT);
}
__device__ __forceinline__ void cohStore(u64* p, u64 v) {
    __hip_atomic_store(p, v, __ATOMIC_RELAXED, __HIP_MEMORY_SCOPE_AGENT);
}
__device__ __forceinline__ float fsigmoid(float x) {
    return __builtin_amdgcn_rcpf(1.f + __expf(-x));
}
__device__ __forceinline__ float ftanh(float x) {
    float e = __expf(2.f * fabsf(x));           // +inf ok -> t = 1
    float t = 1.f - 2.f * __builtin_amdgcn_rcpf(e + 1.f);
    return copysignf(t, x);
}

// ---------------------------------------------------------------------------
// Tiled fp32 GEMM (final projection): C[M][N] = A[M][K] * B[N][K]^T + bias[n]
// ---------------------------------------------------------------------------
template <int BM, int BN, int BK>
__global__ __launch_bounds__(256)
void gemm_abt(const float* __restrict__ A, const float* __restrict__ B,
              const float* __restrict__ bias1,
              float* __restrict__ C, int M, int N, int K) {
    constexpr int NTX = BN / 4;
    constexpr int NTY = 256 / NTX;
    constexpr int TM  = BM / NTY;
    __shared__ float As[BM][BK + 1];
    __shared__ float Bs[BN][BK + 1];

    const int tid = threadIdx.x;
    const int tx = tid % NTX;
    const int ty = tid / NTX;
    const int m0 = blockIdx.y * BM;
    const int n0 = blockIdx.x * BN;

    float acc[TM][4];
    #pragma unroll
    for (int i = 0; i < TM; ++i)
        #pragma unroll
        for (int j = 0; j < 4; ++j) acc[i][j] = 0.f;

    for (int k0 = 0; k0 < K; k0 += BK) {
        constexpr int AV = BM * BK / 4;
        #pragma unroll
        for (int i = tid; i < AV; i += 256) {
            int r = i / (BK / 4), c4 = i % (BK / 4);
            float4 v = *(const float4*)(A + (size_t)(m0 + r) * K + k0 + c4 * 4);
            As[r][c4 * 4 + 0] = v.x; As[r][c4 * 4 + 1] = v.y;
            As[r][c4 * 4 + 2] = v.z; As[r][c4 * 4 + 3] = v.w;
        }
        constexpr int BV = BN * BK / 4;
        #pragma unroll
        for (int i = tid; i < BV; i += 256) {
            int r = i / (BK / 4), c4 = i % (BK / 4);
            float4 v = *(const float4*)(B + (size_t)(n0 + r) * K + k0 + c4 * 4);
            Bs[r][c4 * 4 + 0] = v.x; Bs[r][c4 * 4 + 1] = v.y;
            Bs[r][c4 * 4 + 2] = v.z; Bs[r][c4 * 4 + 3] = v.w;
        }
        __syncthreads();
        #pragma unroll
        for (int kk = 0; kk < BK; ++kk) {
            float a[TM], b[4];
            #pragma unroll
            for (int i = 0; i < TM; ++i) a[i] = As[ty * TM + i][kk];
            #pragma unroll
            for (int j = 0; j < 4; ++j) b[j] = Bs[tx * 4 + j][kk];
            #pragma unroll
            for (int i = 0; i < TM; ++i)
                #pragma unroll
                for (int j = 0; j < 4; ++j) acc[i][j] += a[i] * b[j];
        }
        __syncthreads();
    }

    #pragma unroll
    for (int j = 0; j < 4; ++j) {
        float bv = bias1 ? bias1[n0 + tx * 4 + j] : 0.f;
        #pragma unroll
        for (int i = 0; i < TM; ++i) acc[i][j] += bv;
    }
    #pragma unroll
    for (int i = 0; i < TM; ++i) {
        int m = m0 + ty * TM + i;
        float4 v = make_float4(acc[i][0], acc[i][1], acc[i][2], acc[i][3]);
        *(float4*)(C + (size_t)m * N + n0 + tx * 4) = v;
    }
}

// ---------------------------------------------------------------------------
__global__ void unpack_h(const u64* __restrict__ hp, float* __restrict__ out,
                         int n) {
    int i = blockIdx.x * blockDim.x + threadIdx.x;
    if (i < n) out[i] = __uint_as_float((unsigned)hp[i]);
}

// ---------------------------------------------------------------------------
__global__ __launch_bounds__(NTH, 2)
void lstm_fused(const float* __restrict__ seq,
                const float* __restrict__ Wih1, const float* __restrict__ Whh1,
                const float* __restrict__ bih1, const float* __restrict__ bhh1,
                const float* __restrict__ Wih2, const float* __restrict__ Whh2,
                const float* __restrict__ bih2, const float* __restrict__ bhh2,
                const float* __restrict__ Wih3, const float* __restrict__ Whh3,
                const float* __restrict__ bih3, const float* __restrict__ bhh3,
                u64* __restrict__ hp) {
    __shared__ __align__(16) float h_lds[2][1024];
    __shared__ __align__(16) float x_lds[2][32];

    const int blk   = blockIdx.x;
    const int layer = blk >> 5;
    const int g     = blk & 31;
    const int tid   = threadIdx.x;
    const int wv    = tid >> 6;
    const int lane  = tid & 63;
    const int rl    = lane >> 3;    // row_local 0..7 = gate*2 + cl
    const int j     = lane & 7;     // k-chunk
    const int gate  = rl >> 1;
    const int cl    = rl & 1;
    const int col   = g * 16 + 2 * wv + cl;       // this wave's h column
    const int grow  = gate * HDIM + col;          // global gate row

    const float* Wih = layer == 0 ? Wih1 : (layer == 1 ? Wih2 : Wih3);
    const float* Whh = layer == 0 ? Whh1 : (layer == 1 ? Whh2 : Whh3);
    const float* bih = layer == 0 ? bih1 : (layer == 1 ? bih2 : bih3);
    const float* bhh = layer == 0 ? bhh1 : (layer == 1 ? bhh2 : bhh3);

    // ---- weights into registers ----
    float w[128];
    #pragma unroll
    for (int m = 0; m < 128; ++m) w[m] = 0.f;
    if (layer == 0) {
        // h chunk: 64 k  -> w[0..63];  x chunk: 4 k -> w[64..67]
        const float* wp = Whh + (size_t)grow * HDIM + j * 64;
        #pragma unroll
        for (int m = 0; m < 16; ++m) {
            float4 v = ((const float4*)wp)[m];
            w[4*m+0]=v.x; w[4*m+1]=v.y; w[4*m+2]=v.z; w[4*m+3]=v.w;
        }
        float4 xv = *(const float4*)(Wih + (size_t)grow * 32 + j * 4);
        w[64]=xv.x; w[65]=xv.y; w[66]=xv.z; w[67]=xv.w;
    } else {
        const float* wp = (j < 4)
            ? Wih + (size_t)grow * HDIM + j * 128
            : Whh + (size_t)grow * HDIM + (j - 4) * 128;
        #pragma unroll
        for (int m = 0; m < 32; ++m) {
            float4 v = ((const float4*)wp)[m];
            w[4*m+0]=v.x; w[4*m+1]=v.y; w[4*m+2]=v.z; w[4*m+3]=v.w;
        }
    }
    #pragma unroll
    for (int m = 0; m < 128; ++m) asm volatile("" : "+v"(w[m]));

    const float brow = bih[grow] + bhh[grow];   // bias of this lane's row

    u64*       hpOwn  = hp + (size_t)layer * T_SEQ * HDIM;
    const u64* hpPrev = hp + (size_t)(layer > 0 ? layer - 1 : 0) * T_SEQ * HDIM;

    float c = 0.f;   // cell state (lanes 0 and 8 of each wave)

    for (unsigned t = 0; t < T_SEQ; ++t) {
        const int pb = t & 1;
        // ---- stage inputs (poll fused with data read) ----
        if (layer == 0) {
            float hv = 0.f;
            if (t > 0) {
                const u64* ph = hpOwn + (size_t)(t - 1) * HDIM + tid;
                u64 v;
                do { v = cohLoad(ph); } while ((unsigned)(v >> 32) != t);
                hv = __uint_as_float((unsigned)v);
            }
            h_lds[pb][tid] = hv;
            if (wv == 7 && lane < 32)
                x_lds[pb][lane] = seq[(size_t)t * 32 + lane];
        } else {
            const u64* px = hpPrev + (size_t)t * HDIM + tid;
            u64 va;
            if (t > 0) {
                const u64* ph = hpOwn + (size_t)(t - 1) * HDIM + tid;
                u64 vb; bool ra = false, rb = false;
                for (;;) {
                    if (!ra) { va = cohLoad(px); ra = ((unsigned)(va >> 32) == t + 1u); }
                    if (!rb) { vb = cohLoad(ph); rb = ((unsigned)(vb >> 32) == t); }
                    if (ra & rb) break;
                }
                h_lds[pb][HDIM + tid] = __uint_as_float((unsigned)vb);
            } else {
                do { va = cohLoad(px); } while ((unsigned)(va >> 32) != 1u);
                h_lds[pb][HDIM + tid] = 0.f;
            }
            h_lds[pb][tid] = __uint_as_float((unsigned)va);
        }
        __syncthreads();

        // ---- full-row dot inside the wave ----
        float p = 0.f;
        if (layer == 0) {
            const float4* base = (const float4*)(h_lds[pb]) + j * 16;
            #pragma unroll
            for (int i = 0; i < 16; ++i) {
                int idx = (i + 2 * j) & 15;     // 2-way alias only (free)
                float4 hv = base[idx];
                p += w[4*idx+0]*hv.x + w[4*idx+1]*hv.y
                   + w[4*idx+2]*hv.z + w[4*idx+3]*hv.w;
            }
            float4 xv = ((const float4*)x_lds[pb])[j];
            p += w[64]*xv.x + w[65]*xv.y + w[66]*xv.z + w[67]*xv.w;
        } else {
            const float4* base = (const float4*)(h_lds[pb]) + j * 32;
            #pragma unroll
            for (int i = 0; i < 32; ++i) {
                int idx = (i + j) & 31;         // 8 groups -> disjoint banks
                float4 hv = base[idx];
                p += w[4*idx+0]*hv.x + w[4*idx+1]*hv.y
                   + w[4*idx+2]*hv.z + w[4*idx+3]*hv.w;
            }
        }
        // ---- 8-lane butterfly: row total in every lane of the group ----
        p += __shfl_xor(p, 1, 64);
        p += __shfl_xor(p, 2, 64);
        p += __shfl_xor(p, 4, 64);
        float tot = p + brow;

        // ---- gather 4 gates of this wave's 2 columns; lanes 0,8 finish ----
        float af = __shfl(tot, lane + 16, 64);
        float ag = __shfl(tot, lane + 32, 64);
        float ao = __shfl(tot, lane + 48, 64);
        if ((lane & 55) == 0) {                 // lane 0 (cl=0) or 8 (cl=1)
            float iv = fsigmoid(tot);
            float fv = fsigmoid(af);
            float gv = ftanh(ag);
            float ov = fsigmoid(ao);
            c = fv * c + iv * gv;
            float h = ov * ftanh(c);
            u64 pkt = (u64)__float_as_uint(h) | ((u64)(t + 1u) << 32);
            cohStore(hpOwn + (size_t)t * HDIM + col, pkt);
        }
        // single barrier per step: next stage writes the other buffer.
    }
}

// ---------------------------------------------------------------------------
extern "C" void kernel_launch(void* const* d_in, const int* in_sizes, int n_in,
                              void* d_out, int out_size, void* d_ws, size_t ws_size,
                              hipStream_t stream) {
    const float* seq   = (const float*)d_in[0];
    const float* W_ih1 = (const float*)d_in[1];
    const float* W_hh1 = (const float*)d_in[2];
    const float* b_ih1 = (const float*)d_in[3];
    const float* b_hh1 = (const float*)d_in[4];
    const float* W_ih2 = (const float*)d_in[5];
    const float* W_hh2 = (const float*)d_in[6];
    const float* b_ih2 = (const float*)d_in[7];
    const float* b_hh2 = (const float*)d_in[8];
    const float* W_ih3 = (const float*)d_in[9];
    const float* W_hh3 = (const float*)d_in[10];
    const float* b_ih3 = (const float*)d_in[11];
    const float* b_hh3 = (const float*)d_in[12];
    const float* W_out = (const float*)d_in[13];
    const float* b_out = (const float*)d_in[14];
    float* out = (float*)d_out;

    // Workspace: hp[3][T][512] packed u64 (50.3MB); hs2 floats reuse the
    // dead layer-0 packed region after the recurrence.
    u64*   hp   = (u64*)d_ws;
    float* hs2f = (float*)d_ws;
    const u64* hp2 = hp + (size_t)2 * T_SEQ * HDIM;

    hipMemsetAsync(hp, 0, (size_t)3 * T_SEQ * HDIM * sizeof(u64), stream);

    lstm_fused<<<3 * NWG_L, NTH, 0, stream>>>(
        seq, W_ih1, W_hh1, b_ih1, b_hh1, W_ih2, W_hh2, b_ih2, b_hh2,
        W_ih3, W_hh3, b_ih3, b_hh3, hp);

    const int n = T_SEQ * HDIM;
    unpack_h<<<(n + 255) / 256, 256, 0, stream>>>(hp2, hs2f, n);

    gemm_abt<64, 32, 32><<<dim3(1, T_SEQ / 64), 256, 0, stream>>>(
        hs2f, W_out, b_out, out, T_SEQ, 32, HDIM);
}

// Round 5
// 10045.110 us; speedup vs baseline: 6.9464x; 6.9464x over previous
//
#include <hip/hip_runtime.h>

// LSTM T=4096, IN=32, H=512, OUT=32, 3 layers + projection.
// R5 = R4 structure with the scratch-spill bug fixed.
//   R4 post-mortem: dot loop indexed private w[] with a RUNTIME index
//   ((i+j)&31, j=lane) -> LLVM demoted w[] to scratch; VGPR=72, WRITE_SIZE
//   +120MB of spill traffic, 8x regression. Fix: apply the bank-stagger
//   permutation at WEIGHT LOAD time (global addresses may depend on lane),
//   so the dot loop indexes w[] with loop constants only.
// Layout: 96 WGs x 512 thr; layer=blk>>5, g=blk&31 owns 16 h-columns.
//   Wave wv owns columns {g*16+2wv, +1}, 8 gate rows; lane = rl*8 + j,
//   rl=gate*2+cl, j=k-chunk. Full row dot in-wave -> 3 shfl_xor reduce,
//   one barrier/step (double-buffered LDS), per-wave gate tail.
// Handoff: packed u64 {seq-tag:32 | value:32} relaxed agent-scope atomics
//   (per-instr coherent; no cache-wide fences; safe under XCD L2 split).

#define T_SEQ 4096
#define HDIM  512
#define NWG_L 32
#define NTH   512

typedef unsigned long long u64;

__device__ __forceinline__ u64 cohLoad(const u64* p) {
    return __hip_atomic_load(p, __ATOMIC_RELAXED, __HIP_MEMORY_SCOPE_AGENT);
}
__device__ __forceinline__ void cohStore(u64* p, u64 v) {
    __hip_atomic_store(p, v, __ATOMIC_RELAXED, __HIP_MEMORY_SCOPE_AGENT);
}
__device__ __forceinline__ float fsigmoid(float x) {
    return __builtin_amdgcn_rcpf(1.f + __expf(-x));
}
__device__ __forceinline__ float ftanh(float x) {
    float e = __expf(2.f * fabsf(x));           // +inf ok -> t = 1
    float t = 1.f - 2.f * __builtin_amdgcn_rcpf(e + 1.f);
    return copysignf(t, x);
}

// ---------------------------------------------------------------------------
// Tiled fp32 GEMM (final projection): C[M][N] = A[M][K] * B[N][K]^T + bias[n]
// ---------------------------------------------------------------------------
template <int BM, int BN, int BK>
__global__ __launch_bounds__(256)
void gemm_abt(const float* __restrict__ A, const float* __restrict__ B,
              const float* __restrict__ bias1,
              float* __restrict__ C, int M, int N, int K) {
    constexpr int NTX = BN / 4;
    constexpr int NTY = 256 / NTX;
    constexpr int TM  = BM / NTY;
    __shared__ float As[BM][BK + 1];
    __shared__ float Bs[BN][BK + 1];

    const int tid = threadIdx.x;
    const int tx = tid % NTX;
    const int ty = tid / NTX;
    const int m0 = blockIdx.y * BM;
    const int n0 = blockIdx.x * BN;

    float acc[TM][4];
    #pragma unroll
    for (int i = 0; i < TM; ++i)
        #pragma unroll
        for (int j = 0; j < 4; ++j) acc[i][j] = 0.f;

    for (int k0 = 0; k0 < K; k0 += BK) {
        constexpr int AV = BM * BK / 4;
        #pragma unroll
        for (int i = tid; i < AV; i += 256) {
            int r = i / (BK / 4), c4 = i % (BK / 4);
            float4 v = *(const float4*)(A + (size_t)(m0 + r) * K + k0 + c4 * 4);
            As[r][c4 * 4 + 0] = v.x; As[r][c4 * 4 + 1] = v.y;
            As[r][c4 * 4 + 2] = v.z; As[r][c4 * 4 + 3] = v.w;
        }
        constexpr int BV = BN * BK / 4;
        #pragma unroll
        for (int i = tid; i < BV; i += 256) {
            int r = i / (BK / 4), c4 = i % (BK / 4);
            float4 v = *(const float4*)(B + (size_t)(n0 + r) * K + k0 + c4 * 4);
            Bs[r][c4 * 4 + 0] = v.x; Bs[r][c4 * 4 + 1] = v.y;
            Bs[r][c4 * 4 + 2] = v.z; Bs[r][c4 * 4 + 3] = v.w;
        }
        __syncthreads();
        #pragma unroll
        for (int kk = 0; kk < BK; ++kk) {
            float a[TM], b[4];
            #pragma unroll
            for (int i = 0; i < TM; ++i) a[i] = As[ty * TM + i][kk];
            #pragma unroll
            for (int j = 0; j < 4; ++j) b[j] = Bs[tx * 4 + j][kk];
            #pragma unroll
            for (int i = 0; i < TM; ++i)
                #pragma unroll
                for (int j = 0; j < 4; ++j) acc[i][j] += a[i] * b[j];
        }
        __syncthreads();
    }

    #pragma unroll
    for (int j = 0; j < 4; ++j) {
        float bv = bias1 ? bias1[n0 + tx * 4 + j] : 0.f;
        #pragma unroll
        for (int i = 0; i < TM; ++i) acc[i][j] += bv;
    }
    #pragma unroll
    for (int i = 0; i < TM; ++i) {
        int m = m0 + ty * TM + i;
        float4 v = make_float4(acc[i][0], acc[i][1], acc[i][2], acc[i][3]);
        *(float4*)(C + (size_t)m * N + n0 + tx * 4) = v;
    }
}

// ---------------------------------------------------------------------------
__global__ void unpack_h(const u64* __restrict__ hp, float* __restrict__ out,
                         int n) {
    int i = blockIdx.x * blockDim.x + threadIdx.x;
    if (i < n) out[i] = __uint_as_float((unsigned)hp[i]);
}

// ---------------------------------------------------------------------------
__global__ __launch_bounds__(NTH, 2)
void lstm_fused(const float* __restrict__ seq,
                const float* __restrict__ Wih1, const float* __restrict__ Whh1,
                const float* __restrict__ bih1, const float* __restrict__ bhh1,
                const float* __restrict__ Wih2, const float* __restrict__ Whh2,
                const float* __restrict__ bih2, const float* __restrict__ bhh2,
                const float* __restrict__ Wih3, const float* __restrict__ Whh3,
                const float* __restrict__ bih3, const float* __restrict__ bhh3,
                u64* __restrict__ hp) {
    __shared__ __align__(16) float h_lds[2][1024];
    __shared__ __align__(16) float x_lds[2][32];

    const int blk   = blockIdx.x;
    const int layer = blk >> 5;
    const int g     = blk & 31;
    const int tid   = threadIdx.x;
    const int wv    = tid >> 6;
    const int lane  = tid & 63;
    const int rl    = lane >> 3;    // row_local 0..7 = gate*2 + cl
    const int j     = lane & 7;     // k-chunk
    const int gate  = rl >> 1;
    const int cl    = rl & 1;
    const int col   = g * 16 + 2 * wv + cl;       // this wave's h column
    const int grow  = gate * HDIM + col;          // global gate row

    const float* Wih = layer == 0 ? Wih1 : (layer == 1 ? Wih2 : Wih3);
    const float* Whh = layer == 0 ? Whh1 : (layer == 1 ? Whh2 : Whh3);
    const float* bih = layer == 0 ? bih1 : (layer == 1 ? bih2 : bih3);
    const float* bhh = layer == 0 ? bhh1 : (layer == 1 ? bhh2 : bhh3);

    // ---- weights into registers, PERMUTED so the dot loop reads w[i]
    //      (loop-constant) while LDS is read staggered (bank-conflict-free).
    float w[128];
    #pragma unroll
    for (int m = 0; m < 128; ++m) w[m] = 0.f;
    if (layer == 0) {
        // h chunk: 64 k -> w[0..63] permuted by (i + 2j)&15; x: w[64..67]
        const float* wp = Whh + (size_t)grow * HDIM + j * 64;
        #pragma unroll
        for (int i = 0; i < 16; ++i) {
            int src = (i + 2 * j) & 15;                  // compile-safe: src
            float4 v = ((const float4*)wp)[src];         // is a GLOBAL index
            w[4*i+0]=v.x; w[4*i+1]=v.y; w[4*i+2]=v.z; w[4*i+3]=v.w;
        }
        float4 xv = *(const float4*)(Wih + (size_t)grow * 32 + j * 4);
        w[64]=xv.x; w[65]=xv.y; w[66]=xv.z; w[67]=xv.w;
    } else {
        const float* wp = (j < 4)
            ? Wih + (size_t)grow * HDIM + j * 128
            : Whh + (size_t)grow * HDIM + (j - 4) * 128;
        #pragma unroll
        for (int i = 0; i < 32; ++i) {
            int src = (i + j) & 31;
            float4 v = ((const float4*)wp)[src];
            w[4*i+0]=v.x; w[4*i+1]=v.y; w[4*i+2]=v.z; w[4*i+3]=v.w;
        }
    }
    #pragma unroll
    for (int m = 0; m < 128; ++m) asm volatile("" : "+v"(w[m]));

    const float brow = bih[grow] + bhh[grow];   // bias of this lane's row

    u64*       hpOwn  = hp + (size_t)layer * T_SEQ * HDIM;
    const u64* hpPrev = hp + (size_t)(layer > 0 ? layer - 1 : 0) * T_SEQ * HDIM;

    float c = 0.f;   // cell state (lanes 0 and 8 of each wave)

    for (unsigned t = 0; t < T_SEQ; ++t) {
        const int pb = t & 1;
        // ---- stage inputs (poll fused with data read) ----
        if (layer == 0) {
            float hv = 0.f;
            if (t > 0) {
                const u64* ph = hpOwn + (size_t)(t - 1) * HDIM + tid;
                u64 v;
                do { v = cohLoad(ph); } while ((unsigned)(v >> 32) != t);
                hv = __uint_as_float((unsigned)v);
            }
            h_lds[pb][tid] = hv;
            if (wv == 7 && lane < 32)
                x_lds[pb][lane] = seq[(size_t)t * 32 + lane];
        } else {
            const u64* px = hpPrev + (size_t)t * HDIM + tid;
            u64 va;
            if (t > 0) {
                const u64* ph = hpOwn + (size_t)(t - 1) * HDIM + tid;
                u64 vb; bool ra = false, rb = false;
                for (;;) {
                    if (!ra) { va = cohLoad(px); ra = ((unsigned)(va >> 32) == t + 1u); }
                    if (!rb) { vb = cohLoad(ph); rb = ((unsigned)(vb >> 32) == t); }
                    if (ra & rb) break;
                }
                h_lds[pb][HDIM + tid] = __uint_as_float((unsigned)vb);
            } else {
                do { va = cohLoad(px); } while ((unsigned)(va >> 32) != 1u);
                h_lds[pb][HDIM + tid] = 0.f;
            }
            h_lds[pb][tid] = __uint_as_float((unsigned)va);
        }
        __syncthreads();

        // ---- full-row dot in-wave; w index is LOOP-CONSTANT (no scratch) ----
        float p = 0.f;
        if (layer == 0) {
            const float4* base = (const float4*)(h_lds[pb]) + j * 16;
            #pragma unroll
            for (int i = 0; i < 16; ++i) {
                float4 hv = base[(i + 2 * j) & 15];   // LDS: staggered, free
                p += w[4*i+0]*hv.x + w[4*i+1]*hv.y
                   + w[4*i+2]*hv.z + w[4*i+3]*hv.w;
            }
            float4 xv = ((const float4*)x_lds[pb])[j];
            p += w[64]*xv.x + w[65]*xv.y + w[66]*xv.z + w[67]*xv.w;
        } else {
            const float4* base = (const float4*)(h_lds[pb]) + j * 32;
            #pragma unroll
            for (int i = 0; i < 32; ++i) {
                float4 hv = base[(i + j) & 31];       // 8 groups, disjoint banks
                p += w[4*i+0]*hv.x + w[4*i+1]*hv.y
                   + w[4*i+2]*hv.z + w[4*i+3]*hv.w;
            }
        }
        // ---- 8-lane butterfly: row total in every lane of the group ----
        p += __shfl_xor(p, 1, 64);
        p += __shfl_xor(p, 2, 64);
        p += __shfl_xor(p, 4, 64);
        float tot = p + brow;

        // ---- gather 4 gates of this wave's 2 columns; lanes 0,8 finish ----
        float af = __shfl(tot, lane + 16, 64);
        float ag = __shfl(tot, lane + 32, 64);
        float ao = __shfl(tot, lane + 48, 64);
        if ((lane & 55) == 0) {                 // lane 0 (cl=0) or 8 (cl=1)
            float iv = fsigmoid(tot);
            float fv = fsigmoid(af);
            float gv = ftanh(ag);
            float ov = fsigmoid(ao);
            c = fv * c + iv * gv;
            float h = ov * ftanh(c);
            u64 pkt = (u64)__float_as_uint(h) | ((u64)(t + 1u) << 32);
            cohStore(hpOwn + (size_t)t * HDIM + col, pkt);
        }
        // single barrier per step: next stage writes the other buffer.
    }
}

// ---------------------------------------------------------------------------
extern "C" void kernel_launch(void* const* d_in, const int* in_sizes, int n_in,
                              void* d_out, int out_size, void* d_ws, size_t ws_size,
                              hipStream_t stream) {
    const float* seq   = (const float*)d_in[0];
    const float* W_ih1 = (const float*)d_in[1];
    const float* W_hh1 = (const float*)d_in[2];
    const float* b_ih1 = (const float*)d_in[3];
    const float* b_hh1 = (const float*)d_in[4];
    const float* W_ih2 = (const float*)d_in[5];
    const float* W_hh2 = (const float*)d_in[6];
    const float* b_ih2 = (const float*)d_in[7];
    const float* b_hh2 = (const float*)d_in[8];
    const float* W_ih3 = (const float*)d_in[9];
    const float* W_hh3 = (const float*)d_in[10];
    const float* b_ih3 = (const float*)d_in[11];
    const float* b_hh3 = (const float*)d_in[12];
    const float* W_out = (const float*)d_in[13];
    const float* b_out = (const float*)d_in[14];
    float* out = (float*)d_out;

    // Workspace: hp[3][T][512] packed u64 (50.3MB); hs2 floats reuse the
    // dead layer-0 packed region after the recurrence.
    u64*   hp   = (u64*)d_ws;
    float* hs2f = (float*)d_ws;
    const u64* hp2 = hp + (size_t)2 * T_SEQ * HDIM;

    hipMemsetAsync(hp, 0, (size_t)3 * T_SEQ * HDIM * sizeof(u64), stream);

    lstm_fused<<<3 * NWG_L, NTH, 0, stream>>>(
        seq, W_ih1, W_hh1, b_ih1, b_hh1, W_ih2, W_hh2, b_ih2, b_hh2,
        W_ih3, W_hh3, b_ih3, b_hh3, hp);

    const int n = T_SEQ * HDIM;
    unpack_h<<<(n + 255) / 256, 256, 0, stream>>>(hp2, hs2f, n);

    gemm_abt<64, 32, 32><<<dim3(1, T_SEQ / 64), 256, 0, stream>>>(
        hs2f, W_out, b_out, out, T_SEQ, 32, HDIM);
}